// Round 7
// baseline (151.130 us; speedup 1.0000x reference)
//
#include <hip/hip_runtime.h>
#include <math.h>

#define NB 32
#define NT 2048
#define NC 1024
#define NH 8
#define ND 128
#define TCH 16                       // t-chunks per batch; chunk = 128 rows
#define SCALE_F 0.08838834764831845f // 1/sqrt(128)

__device__ __forceinline__ float wredsum(float v) {
#pragma unroll
  for (int off = 32; off > 0; off >>= 1) v += __shfl_xor(v, off, 64);
  return v;
}

// Fused q + split-K wq partial. Block (h,dq) computes q[dbase..dbase+32)
// itself (q_w rows read exactly once across the grid), then
// wqp[dq][h*NC+c] = sum_{d in range} q[d]*kv_w[d*NC+c].
__global__ __launch_bounds__(256) void k_wqp(const float* __restrict__ qt,
                                             const float* __restrict__ q_w,
                                             const float* __restrict__ q_b,
                                             const float* __restrict__ kv_w,
                                             float* __restrict__ qout,
                                             float* __restrict__ wqp) {
  __shared__ float qs[32];
  int h = blockIdx.x >> 2, dq = blockIdx.x & 3;
  int tid = threadIdx.x;
  int dbase = h * ND + dq * 32;
  {
    int row = tid >> 3;  // 32 rows x 8 threads
    int cg = tid & 7;
    const float4* qw4 = (const float4*)(q_w + (size_t)(dbase + row) * NC);
    const float4* qt4 = (const float4*)qt;
    float p = 0.f;
#pragma unroll 8
    for (int j = 0; j < 32; ++j) {
      float4 wv = qw4[cg * 32 + j];
      float4 av = qt4[cg * 32 + j];
      p += av.x * wv.x + av.y * wv.y + av.z * wv.z + av.w * wv.w;
    }
    p += __shfl_xor(p, 1, 64);
    p += __shfl_xor(p, 2, 64);
    p += __shfl_xor(p, 4, 64);
    if (cg == 0) qs[row] = p + q_b[dbase + row];
  }
  __syncthreads();
  if (tid < 32) qout[dbase + tid] = qs[tid];
  const float4* kw4 = (const float4*)kv_w;
  float4 acc = make_float4(0.f, 0.f, 0.f, 0.f);
#pragma unroll 8
  for (int dd = 0; dd < 32; ++dd) {
    float qv = qs[dd];
    float4 kv = kw4[(size_t)(dbase + dd) * 256 + tid];
    acc.x = fmaf(qv, kv.x, acc.x); acc.y = fmaf(qv, kv.y, acc.y);
    acc.z = fmaf(qv, kv.z, acc.z); acc.w = fmaf(qv, kv.w, acc.w);
  }
  ((float4*)wqp)[dq * 2048 + h * 256 + tid] = acc;
}

// Single pass over x. Block = (b,tc): 128 rows. Wave w owns heads {2w,2w+1}.
// 32 steps x 4 rows, LDS double buffer (2 x 16 KB), 1 sync/step:
// [issue loads s+1] [compute s from slot s&1] [write slot s^1] [sync].
// Prefetch budget = full compute phase (~1500 cyc) > HBM latency (~900).
__global__ __launch_bounds__(256, 2) void k_fused(
    const float* __restrict__ x, const int* __restrict__ mask,
    const float* __restrict__ wqp, const float* __restrict__ q,
    const float* __restrict__ kv_b,
    float* __restrict__ S, float* __restrict__ partAcc,
    float* __restrict__ partML) {
  __shared__ float4 xs4[2 * 1024];  // 2 slots x 4 rows x 256 float4 = 32 KB
  int bi = blockIdx.x;  // b*TCH + tc
  int b = bi >> 4;
  int tc = bi & (TCH - 1);
  int tid = threadIdx.x;
  int w = tid >> 6, lane = tid & 63;
  int h0 = w * 2;
  int tbase = tc * 128;

  // wq fragments: sum of 4 split-K partials (L2-hot)
  const float4* wqp4 = (const float4*)wqp;
  float4 wqv[2][4];
#pragma unroll
  for (int hh = 0; hh < 2; ++hh)
#pragma unroll
    for (int j = 0; j < 4; ++j) {
      int idx = (h0 + hh) * 256 + lane + 64 * j;
      float4 s0 = wqp4[idx], s1 = wqp4[2048 + idx];
      float4 s2 = wqp4[4096 + idx], s3 = wqp4[6144 + idx];
      wqv[hh][j] = make_float4((s0.x + s1.x) + (s2.x + s3.x),
                               (s0.y + s1.y) + (s2.y + s3.y),
                               (s0.z + s1.z) + (s2.z + s3.z),
                               (s0.w + s1.w) + (s2.w + s3.w));
    }
  // qkb[h] = q[h,:].kv_b[h,:] in-wave
  float qkbv[2];
#pragma unroll
  for (int hh = 0; hh < 2; ++hh) {
    float p = 0.f;
    if (lane < 32) {
      float4 qv = ((const float4*)(q + (h0 + hh) * ND))[lane];
      float4 bv = ((const float4*)(kv_b + (h0 + hh) * ND))[lane];
      p = qv.x * bv.x + qv.y * bv.y + qv.z * bv.z + qv.w * bv.w;
    }
    qkbv[hh] = wredsum(p);
  }

  float m[2] = {-INFINITY, -INFINITY};
  float l[2] = {0.f, 0.f};
  float4 acc[2][4];
#pragma unroll
  for (int hh = 0; hh < 2; ++hh)
#pragma unroll
    for (int j = 0; j < 4; ++j) acc[hh][j] = make_float4(0.f, 0.f, 0.f, 0.f);
  float4 sreg[2];
  sreg[0] = make_float4(0.f, 0.f, 0.f, 0.f);
  sreg[1] = make_float4(0.f, 0.f, 0.f, 0.f);

  const float4* x4 = (const float4*)(x + (size_t)(b * NT + tbase) * NC);
  const int* mrow = mask + b * NT + tbase;

  // prologue: rows 0..3 -> slot 0
  {
    float4 P[4];
#pragma unroll
    for (int k = 0; k < 4; ++k) P[k] = x4[k * 256 + tid];
#pragma unroll
    for (int k = 0; k < 4; ++k) xs4[k * 256 + tid] = P[k];
  }
  __syncthreads();

  for (int step = 0; step < 32; ++step) {
    int s = step & 1;
    float4 Pn[4];
    if (step < 31) {
#pragma unroll
      for (int k = 0; k < 4; ++k) Pn[k] = x4[((step + 1) * 4 + k) * 256 + tid];
    }
    int t0 = tbase + step * 4;
    int mk[4];
#pragma unroll
    for (int r = 0; r < 4; ++r) mk[r] = mrow[step * 4 + r];
    // xv held in regs across dot+acc phases (single LDS read per step)
    float4 xv[4][4];
#pragma unroll
    for (int r = 0; r < 4; ++r)
#pragma unroll
      for (int j = 0; j < 4; ++j)
        xv[r][j] = xs4[s * 1024 + r * 256 + lane + 64 * j];
    float d[2][4];
#pragma unroll
    for (int hh = 0; hh < 2; ++hh)
#pragma unroll
      for (int r = 0; r < 4; ++r) d[hh][r] = 0.f;
#pragma unroll
    for (int j = 0; j < 4; ++j) {
#pragma unroll
      for (int hh = 0; hh < 2; ++hh) {
        float4 wv = wqv[hh][j];
#pragma unroll
        for (int r = 0; r < 4; ++r) {
          d[hh][r] = fmaf(xv[r][j].x, wv.x, d[hh][r]);
          d[hh][r] = fmaf(xv[r][j].y, wv.y, d[hh][r]);
          d[hh][r] = fmaf(xv[r][j].z, wv.z, d[hh][r]);
          d[hh][r] = fmaf(xv[r][j].w, wv.w, d[hh][r]);
        }
      }
    }
    float pp[2][4];
#pragma unroll
    for (int hh = 0; hh < 2; ++hh) {
      float v[4];
#pragma unroll
      for (int r = 0; r < 4; ++r) {
        float dr = wredsum(d[hh][r]);
        float biasr = 2.0f * __expf((float)(t0 + r) * (-3.0f / 2048.0f));
        v[r] = mk[r] ? (dr + qkbv[hh]) * SCALE_F + biasr : -INFINITY;
      }
      if (lane == step) sreg[hh] = make_float4(v[0], v[1], v[2], v[3]);
      float mnew = fmaxf(fmaxf(m[hh], fmaxf(v[0], v[1])), fmaxf(v[2], v[3]));
      if (mnew > m[hh]) {  // wave-uniform
        float r = __expf(m[hh] - mnew);
        l[hh] *= r;
#pragma unroll
        for (int j = 0; j < 4; ++j) {
          acc[hh][j].x *= r; acc[hh][j].y *= r;
          acc[hh][j].z *= r; acc[hh][j].w *= r;
        }
        m[hh] = mnew;
      }
#pragma unroll
      for (int r = 0; r < 4; ++r)
        pp[hh][r] = mk[r] ? __expf(v[r] - m[hh]) : 0.f;
      l[hh] += (pp[hh][0] + pp[hh][1]) + (pp[hh][2] + pp[hh][3]);
    }
#pragma unroll
    for (int j = 0; j < 4; ++j) {
#pragma unroll
      for (int hh = 0; hh < 2; ++hh) {
        float4 a = acc[hh][j];
        a.x = fmaf(pp[hh][0], xv[0][j].x, fmaf(pp[hh][1], xv[1][j].x,
              fmaf(pp[hh][2], xv[2][j].x, fmaf(pp[hh][3], xv[3][j].x, a.x))));
        a.y = fmaf(pp[hh][0], xv[0][j].y, fmaf(pp[hh][1], xv[1][j].y,
              fmaf(pp[hh][2], xv[2][j].y, fmaf(pp[hh][3], xv[3][j].y, a.y))));
        a.z = fmaf(pp[hh][0], xv[0][j].z, fmaf(pp[hh][1], xv[1][j].z,
              fmaf(pp[hh][2], xv[2][j].z, fmaf(pp[hh][3], xv[3][j].z, a.z))));
        a.w = fmaf(pp[hh][0], xv[0][j].w, fmaf(pp[hh][1], xv[1][j].w,
              fmaf(pp[hh][2], xv[2][j].w, fmaf(pp[hh][3], xv[3][j].w, a.w))));
        acc[hh][j] = a;
      }
    }
    // write prefetched rows into the other slot; 1 sync/step
    if (step < 31) {
#pragma unroll
      for (int k = 0; k < 4; ++k) xs4[(s ^ 1) * 1024 + k * 256 + tid] = Pn[k];
    }
    __syncthreads();
  }

  // raw-score store: lane k<32 owns rows tbase+4k..+3 (float4), others junk
  if (lane < 32) {
#pragma unroll
    for (int hh = 0; hh < 2; ++hh)
      ((float4*)(S + ((size_t)(b * NH + h0 + hh)) * NT + tbase))[lane] = sreg[hh];
  }
  float4* pA = (float4*)(partAcc + (size_t)bi * (NH * NC));
#pragma unroll
  for (int hh = 0; hh < 2; ++hh)
#pragma unroll
    for (int j = 0; j < 4; ++j)
      pA[(h0 + hh) * 256 + lane + 64 * j] = acc[hh][j];
  if (lane == 0) {
#pragma unroll
    for (int hh = 0; hh < 2; ++hh) {
      partML[(bi * NH + h0 + hh) * 2] = m[hh];
      partML[(bi * NH + h0 + hh) * 2 + 1] = l[hh];
    }
  }
}

// Merged xa-reduce + attn_weights (ML recomputed per block from L2-hot partML).
// Blocks [0,256): xa role per (b,h); [256,512): attn_weights per (b, 256-t).
__global__ __launch_bounds__(256) void k_xaw(const float* __restrict__ partAcc,
                                             const float* __restrict__ partML,
                                             const float* __restrict__ S,
                                             float* __restrict__ xa,
                                             float* __restrict__ ow) {
  __shared__ float Ms[NH], Is[NH];
  int blk = blockIdx.x;
  int tid = threadIdx.x;
  if (blk < NB * NH) {  // ---- xa role ----
    int b = blk >> 3, h = blk & 7;
    float mv = -INFINITY, lv = 0.f;
    if (tid < TCH) {
      mv = partML[((b * TCH + tid) * NH + h) * 2];
      lv = partML[((b * TCH + tid) * NH + h) * 2 + 1];
    }
    float Mg = mv;
#pragma unroll
    for (int off = 8; off > 0; off >>= 1) Mg = fmaxf(Mg, __shfl_xor(Mg, off, 64));
    float contrib = (tid < TCH && mv != -INFINITY) ? __expf(mv - Mg) * lv : 0.f;
#pragma unroll
    for (int off = 8; off > 0; off >>= 1) contrib += __shfl_xor(contrib, off, 64);
    if (tid == 0) {
      Ms[0] = Mg;
      Is[0] = (contrib > 0.f) ? 1.f / contrib : 0.f;
    }
    __syncthreads();
    float Mgb = Ms[0], inv = Is[0];
    float4 sacc = make_float4(0.f, 0.f, 0.f, 0.f);
    for (int tc = 0; tc < TCH; ++tc) {
      int pi = (b * TCH + tc) * NH + h;
      float mw = partML[pi * 2];
      if (mw == -INFINITY) continue;
      float scl = __expf(mw - Mgb);
      float4 v = ((const float4*)partAcc)[(size_t)pi * 256 + tid];
      sacc.x = fmaf(scl, v.x, sacc.x); sacc.y = fmaf(scl, v.y, sacc.y);
      sacc.z = fmaf(scl, v.z, sacc.z); sacc.w = fmaf(scl, v.w, sacc.w);
    }
    sacc.x *= inv; sacc.y *= inv; sacc.z *= inv; sacc.w *= inv;
    ((float4*)xa)[(size_t)blk * 256 + tid] = sacc;
  } else {  // ---- attn_weights role ----
    int blkb = blk - NB * NH;
    int b = blkb >> 3, tch = blkb & 7;
    int hh = tid >> 4, tcc = tid & 15;  // 8 heads x 16 chunks in tid<128
    float mv = -INFINITY, lv = 0.f;
    if (tid < 128) {
      mv = partML[((b * TCH + tcc) * NH + hh) * 2];
      lv = partML[((b * TCH + tcc) * NH + hh) * 2 + 1];
    }
    float Mg = mv;
#pragma unroll
    for (int off = 8; off > 0; off >>= 1) Mg = fmaxf(Mg, __shfl_xor(Mg, off, 64));
    float contrib = (tid < 128 && mv != -INFINITY) ? __expf(mv - Mg) * lv : 0.f;
#pragma unroll
    for (int off = 8; off > 0; off >>= 1) contrib += __shfl_xor(contrib, off, 64);
    if (tid < 128 && tcc == 0) {
      Ms[hh] = Mg;
      Is[hh] = (contrib > 0.f) ? 1.f / contrib : 0.f;
    }
    __syncthreads();
    int t = tch * 256 + tid;
    float a = 0.f;
#pragma unroll
    for (int h = 0; h < NH; ++h) {
      float s = S[((size_t)(b * NH + h)) * NT + t];
      a += (s == -INFINITY) ? 0.f : __expf(s - Ms[h]) * Is[h];
    }
    ow[(size_t)b * NT + t] = a * 0.125f;
  }
}

// p2[b, hd] = xa[b,h,:].kv_w[NC+hd, :] + kv_b[NC+hd]  (wave per (b,hd))
__global__ __launch_bounds__(256) void k_pv(const float* __restrict__ xa,
                                            const float* __restrict__ kv_w,
                                            const float* __restrict__ kv_b,
                                            float* __restrict__ p2) {
  int gw = (blockIdx.x * 256 + threadIdx.x) >> 6;
  int lane = threadIdx.x & 63;
  if (gw >= NB * NC) return;
  int b = gw >> 10;
  int hd = gw & (NC - 1);
  int h = hd >> 7;
  const float4* a4 = (const float4*)(xa + ((size_t)(b * NH + h)) * NC);
  const float4* w4 = (const float4*)(kv_w + ((size_t)(NC + hd)) * NC);
  float acc = 0.f;
#pragma unroll
  for (int j = 0; j < 4; ++j) {
    float4 a = a4[lane + 64 * j];
    float4 w = w4[lane + 64 * j];
    acc += a.x * w.x + a.y * w.y + a.z * w.z + a.w * w.w;
  }
  acc = wredsum(acc);
  if (lane == 0) p2[(size_t)b * NC + hd] = acc + kv_b[NC + hd];
}

// out[b,i] = p2[b,:].proj_w[i,:] + proj_b[i]  (wave per (b,i))
__global__ __launch_bounds__(256) void k_proj(const float* __restrict__ p2,
                                              const float* __restrict__ proj_w,
                                              const float* __restrict__ proj_b,
                                              float* __restrict__ out) {
  int gw = (blockIdx.x * 256 + threadIdx.x) >> 6;
  int lane = threadIdx.x & 63;
  if (gw >= NB * NC) return;
  int b = gw >> 10;
  int i = gw & (NC - 1);
  const float4* a4 = (const float4*)(p2 + (size_t)b * NC);
  const float4* w4 = (const float4*)(proj_w + (size_t)i * NC);
  float acc = 0.f;
#pragma unroll
  for (int j = 0; j < 4; ++j) {
    float4 a = a4[lane + 64 * j];
    float4 w = w4[lane + 64 * j];
    acc += a.x * w.x + a.y * w.y + a.z * w.z + a.w * w.w;
  }
  acc = wredsum(acc);
  if (lane == 0) out[(size_t)b * NC + i] = acc + proj_b[i];
}

extern "C" void kernel_launch(void* const* d_in, const int* in_sizes, int n_in,
                              void* d_out, int out_size, void* d_ws, size_t ws_size,
                              hipStream_t stream) {
  const float* x = (const float*)d_in[0];
  const int* mask = (const int*)d_in[1];
  const float* qt = (const float*)d_in[2];
  const float* kv_w = (const float*)d_in[3];
  const float* kv_b = (const float*)d_in[4];
  const float* q_w = (const float*)d_in[5];
  const float* q_b = (const float*)d_in[6];
  const float* proj_w = (const float*)d_in[7];
  const float* proj_b = (const float*)d_in[8];
  float* out = (float*)d_out;

  float* ws = (float*)d_ws;
  float* q = ws;                    // 1024
  float* wqp = ws + 1024;           // 32768
  float* S = ws + 33792;            // 524288
  float* partAcc = ws + 558080;     // NB*TCH*NH*NC = 4194304 (16 MiB)
  float* partML = ws + 4752384;     // NB*TCH*NH*2 = 8192
  float* xa = ws + 4760576;         // 262144
  float* p2 = ws + 5022720;         // 32768

  k_wqp<<<32, 256, 0, stream>>>(qt, q_w, q_b, kv_w, q, wqp);
  k_fused<<<NB * TCH, 256, 0, stream>>>(x, mask, wqp, q, kv_b, S, partAcc, partML);
  k_xaw<<<512, 256, 0, stream>>>(partAcc, partML, S, xa, out + NB * NC);
  k_pv<<<(NB * NC) / 4, 256, 0, stream>>>(xa, kv_w, kv_b, p2);
  k_proj<<<(NB * NC) / 4, 256, 0, stream>>>(p2, proj_w, proj_b, out);
}

// Round 8
// 143.919 us; speedup vs baseline: 1.0501x; 1.0501x over previous
//
#include <hip/hip_runtime.h>
#include <math.h>

#define NB 32
#define NT 2048
#define NC 1024
#define NH 8
#define ND 128
#define TCH 32                       // t-chunks per batch; chunk = 64 rows
#define SCALE_F 0.08838834764831845f // 1/sqrt(128)

__device__ __forceinline__ float wredsum(float v) {
#pragma unroll
  for (int off = 32; off > 0; off >>= 1) v += __shfl_xor(v, off, 64);
  return v;
}

// Fused q + split-K wq partial. Block (h,dq) computes q[dbase..dbase+32)
// itself (q_w rows read exactly once across the grid), then
// wqp[dq][h*NC+c] = sum_{d in range} q[d]*kv_w[d*NC+c].
__global__ __launch_bounds__(256) void k_wqp(const float* __restrict__ qt,
                                             const float* __restrict__ q_w,
                                             const float* __restrict__ q_b,
                                             const float* __restrict__ kv_w,
                                             float* __restrict__ qout,
                                             float* __restrict__ wqp) {
  __shared__ float qs[32];
  int h = blockIdx.x >> 2, dq = blockIdx.x & 3;
  int tid = threadIdx.x;
  int dbase = h * ND + dq * 32;
  {
    int row = tid >> 3;  // 32 rows x 8 threads
    int cg = tid & 7;
    const float4* qw4 = (const float4*)(q_w + (size_t)(dbase + row) * NC);
    const float4* qt4 = (const float4*)qt;
    float p = 0.f;
#pragma unroll 8
    for (int j = 0; j < 32; ++j) {
      float4 wv = qw4[cg * 32 + j];
      float4 av = qt4[cg * 32 + j];
      p += av.x * wv.x + av.y * wv.y + av.z * wv.z + av.w * wv.w;
    }
    p += __shfl_xor(p, 1, 64);
    p += __shfl_xor(p, 2, 64);
    p += __shfl_xor(p, 4, 64);
    if (cg == 0) qs[row] = p + q_b[dbase + row];
  }
  __syncthreads();
  if (tid < 32) qout[dbase + tid] = qs[tid];
  const float4* kw4 = (const float4*)kv_w;
  float4 acc = make_float4(0.f, 0.f, 0.f, 0.f);
#pragma unroll 8
  for (int dd = 0; dd < 32; ++dd) {
    float qv = qs[dd];
    float4 kv = kw4[(size_t)(dbase + dd) * 256 + tid];
    acc.x = fmaf(qv, kv.x, acc.x); acc.y = fmaf(qv, kv.y, acc.y);
    acc.z = fmaf(qv, kv.z, acc.z); acc.w = fmaf(qv, kv.w, acc.w);
  }
  ((float4*)wqp)[dq * 2048 + h * 256 + tid] = acc;
}

// Single pass over x (R6-validated geometry: TCH=32, 2-row steps, 16KB dbuf).
// Block = (b,tc): 64 rows. Wave w owns heads {2w,2w+1} over all rows.
// Per step: prefetch next pair to regs, compute from LDS, ds_write, 1 sync.
// Defer-max (THR=8): only rescale l/acc when pmax exceeds m by >8; p <= e^8.
__global__ __launch_bounds__(256, 2) void k_fused(
    const float* __restrict__ x, const int* __restrict__ mask,
    const float* __restrict__ wqp, const float* __restrict__ q,
    const float* __restrict__ kv_b,
    float* __restrict__ S, float* __restrict__ partAcc,
    float* __restrict__ partML) {
  __shared__ float xs[2][2 * NC];  // 16 KB
  int bi = blockIdx.x;  // b*TCH + tc
  int b = bi >> 5;
  int tc = bi & (TCH - 1);
  int tid = threadIdx.x;
  int w = tid >> 6, lane = tid & 63;
  int h0 = w * 2;
  int tbase = tc * 64;

  // wq fragments (sum the 4 split-K partials; L2-hot)
  const float4* wqp4 = (const float4*)wqp;
  float4 wqv[2][4];
#pragma unroll
  for (int hh = 0; hh < 2; ++hh)
#pragma unroll
    for (int j = 0; j < 4; ++j) {
      int idx = (h0 + hh) * 256 + lane + 64 * j;
      float4 s0 = wqp4[idx], s1 = wqp4[2048 + idx];
      float4 s2 = wqp4[4096 + idx], s3 = wqp4[6144 + idx];
      wqv[hh][j] = make_float4((s0.x + s1.x) + (s2.x + s3.x),
                               (s0.y + s1.y) + (s2.y + s3.y),
                               (s0.z + s1.z) + (s2.z + s3.z),
                               (s0.w + s1.w) + (s2.w + s3.w));
    }
  // qkb[h] = q[h,:].kv_b[h,:] in-wave
  float qkbv[2];
#pragma unroll
  for (int hh = 0; hh < 2; ++hh) {
    float p = 0.f;
    if (lane < 32) {
      float4 qv = ((const float4*)(q + (h0 + hh) * ND))[lane];
      float4 bv = ((const float4*)(kv_b + (h0 + hh) * ND))[lane];
      p = qv.x * bv.x + qv.y * bv.y + qv.z * bv.z + qv.w * bv.w;
    }
    qkbv[hh] = wredsum(p);
  }

  float m[2] = {-INFINITY, -INFINITY};
  float l[2] = {0.f, 0.f};
  float4 acc[2][4];
#pragma unroll
  for (int hh = 0; hh < 2; ++hh)
#pragma unroll
    for (int j = 0; j < 4; ++j) acc[hh][j] = make_float4(0.f, 0.f, 0.f, 0.f);
  float sreg[2][2] = {{0.f, 0.f}, {0.f, 0.f}};

  const float4* x4 = (const float4*)(x + (size_t)(b * NT + tbase) * NC);
  const int* mrow = mask + b * NT + tbase;
  float4* xs4 = (float4*)xs;

  // prologue: stage rows 0,1 into slot 0
  {
    float4 s0 = x4[tid], s1 = x4[256 + tid];
    xs4[tid] = s0;
    xs4[256 + tid] = s1;
  }
  __syncthreads();

#pragma unroll 2
  for (int step = 0; step < 32; ++step) {
    int s = step & 1;
    // prefetch next row pair (HBM latency hides under compute below)
    float4 p0v, p1v;
    if (step < 31) {
      p0v = x4[(2 * step + 2) * 256 + tid];
      p1v = x4[(2 * step + 3) * 256 + tid];
    }
    int t0 = tbase + step * 2;
    float4 xv[2][4];
#pragma unroll
    for (int r = 0; r < 2; ++r)
#pragma unroll
      for (int j = 0; j < 4; ++j)
        xv[r][j] = xs4[s * 512 + r * 256 + lane + 64 * j];
    int mk0 = mrow[step * 2];
    int mk1 = mrow[step * 2 + 1];
    float bias0 = 2.0f * __expf((float)t0 * (-3.0f / 2048.0f));
    float bias1 = 2.0f * __expf((float)(t0 + 1) * (-3.0f / 2048.0f));
#pragma unroll
    for (int hh = 0; hh < 2; ++hh) {
      float d0 = 0.f, d1 = 0.f;
#pragma unroll
      for (int j = 0; j < 4; ++j) {
        float4 wv = wqv[hh][j];
        d0 = fmaf(xv[0][j].x, wv.x, d0); d0 = fmaf(xv[0][j].y, wv.y, d0);
        d0 = fmaf(xv[0][j].z, wv.z, d0); d0 = fmaf(xv[0][j].w, wv.w, d0);
        d1 = fmaf(xv[1][j].x, wv.x, d1); d1 = fmaf(xv[1][j].y, wv.y, d1);
        d1 = fmaf(xv[1][j].z, wv.z, d1); d1 = fmaf(xv[1][j].w, wv.w, d1);
      }
      d0 = wredsum(d0);
      d1 = wredsum(d1);
      float v0 = mk0 ? (d0 + qkbv[hh]) * SCALE_F + bias0 : -INFINITY;
      float v1 = mk1 ? (d1 + qkbv[hh]) * SCALE_F + bias1 : -INFINITY;
      sreg[hh][0] = (lane == step) ? v0 : sreg[hh][0];
      sreg[hh][1] = (lane == step) ? v1 : sreg[hh][1];
      // defer-max (T13): rescale only when new max exceeds running m by >8.
      // p bounded by e^8; l/acc stay well inside fp32. wave-uniform branch.
      float pmax = fmaxf(v0, v1);
      if (pmax > m[hh] + 8.0f) {
        float r = __expf(m[hh] - pmax);  // m=-inf -> r=0 zeroes l/acc (ok)
        l[hh] *= r;
#pragma unroll
        for (int j = 0; j < 4; ++j) {
          acc[hh][j].x *= r; acc[hh][j].y *= r;
          acc[hh][j].z *= r; acc[hh][j].w *= r;
        }
        m[hh] = pmax;
      }
      float p0 = mk0 ? __expf(v0 - m[hh]) : 0.f;
      float p1 = mk1 ? __expf(v1 - m[hh]) : 0.f;
      l[hh] += p0 + p1;
#pragma unroll
      for (int j = 0; j < 4; ++j) {
        acc[hh][j].x = fmaf(p0, xv[0][j].x, fmaf(p1, xv[1][j].x, acc[hh][j].x));
        acc[hh][j].y = fmaf(p0, xv[0][j].y, fmaf(p1, xv[1][j].y, acc[hh][j].y));
        acc[hh][j].z = fmaf(p0, xv[0][j].z, fmaf(p1, xv[1][j].z, acc[hh][j].z));
        acc[hh][j].w = fmaf(p0, xv[0][j].w, fmaf(p1, xv[1][j].w, acc[hh][j].w));
      }
    }
    // stage prefetched pair into the other slot; 1 sync/step (double buffer)
    if (step < 31) {
      xs4[(s ^ 1) * 512 + tid] = p0v;
      xs4[(s ^ 1) * 512 + 256 + tid] = p1v;
    }
    __syncthreads();
  }

  // raw-score store: ONLY lanes 0..31 own rows (R4 lesson)
  if (lane < 32) {
#pragma unroll
    for (int hh = 0; hh < 2; ++hh) {
      float2 sv = make_float2(sreg[hh][0], sreg[hh][1]);
      float2* sp = (float2*)(S + ((size_t)(b * NH + h0 + hh)) * NT + tbase);
      sp[lane] = sv;
    }
  }
  float4* pA = (float4*)(partAcc + (size_t)bi * (NH * NC));
#pragma unroll
  for (int hh = 0; hh < 2; ++hh)
#pragma unroll
    for (int j = 0; j < 4; ++j)
      pA[(h0 + hh) * 256 + lane + 64 * j] = acc[hh][j];
  if (lane == 0) {
#pragma unroll
    for (int hh = 0; hh < 2; ++hh) {
      partML[(bi * NH + h0 + hh) * 2] = m[hh];
      partML[(bi * NH + h0 + hh) * 2 + 1] = l[hh];
    }
  }
}

// Merged xa-reduce + attn_weights (ML recomputed per block from L2-hot partML).
// Blocks [0,256): xa role per (b,h); [256,512): attn_weights per (b, 256-t).
__global__ __launch_bounds__(256) void k_xaw(const float* __restrict__ partAcc,
                                             const float* __restrict__ partML,
                                             const float* __restrict__ S,
                                             float* __restrict__ xa,
                                             float* __restrict__ ow) {
  __shared__ float Ms[NH], Is[NH];
  int blk = blockIdx.x;
  int tid = threadIdx.x;
  if (blk < NB * NH) {  // ---- xa role ----
    int b = blk >> 3, h = blk & 7;
    float mv = -INFINITY, lv = 0.f;
    if (tid < 32) {
      mv = partML[((b * TCH + tid) * NH + h) * 2];
      lv = partML[((b * TCH + tid) * NH + h) * 2 + 1];
    }
    float Mg = mv;
#pragma unroll
    for (int off = 16; off > 0; off >>= 1) Mg = fmaxf(Mg, __shfl_xor(Mg, off, 64));
    float contrib = (tid < 32 && mv != -INFINITY) ? __expf(mv - Mg) * lv : 0.f;
#pragma unroll
    for (int off = 16; off > 0; off >>= 1) contrib += __shfl_xor(contrib, off, 64);
    if (tid == 0) {
      Ms[0] = Mg;
      Is[0] = (contrib > 0.f) ? 1.f / contrib : 0.f;
    }
    __syncthreads();
    float Mgb = Ms[0], inv = Is[0];
    float4 sacc = make_float4(0.f, 0.f, 0.f, 0.f);
    for (int tc = 0; tc < TCH; ++tc) {
      int pi = (b * TCH + tc) * NH + h;
      float mw = partML[pi * 2];
      if (mw == -INFINITY) continue;
      float scl = __expf(mw - Mgb);
      float4 v = ((const float4*)partAcc)[(size_t)pi * 256 + tid];
      sacc.x = fmaf(scl, v.x, sacc.x); sacc.y = fmaf(scl, v.y, sacc.y);
      sacc.z = fmaf(scl, v.z, sacc.z); sacc.w = fmaf(scl, v.w, sacc.w);
    }
    sacc.x *= inv; sacc.y *= inv; sacc.z *= inv; sacc.w *= inv;
    ((float4*)xa)[(size_t)blk * 256 + tid] = sacc;
  } else {  // ---- attn_weights role ----
    int blkb = blk - NB * NH;
    int b = blkb >> 3, tch = blkb & 7;
    int hh = tid >> 5, tcc = tid & 31;  // 8 heads x 32 chunks
    float mv = partML[((b * TCH + tcc) * NH + hh) * 2];
    float lv = partML[((b * TCH + tcc) * NH + hh) * 2 + 1];
    float Mg = mv;
#pragma unroll
    for (int off = 16; off > 0; off >>= 1) Mg = fmaxf(Mg, __shfl_xor(Mg, off, 64));
    float contrib = (mv != -INFINITY) ? __expf(mv - Mg) * lv : 0.f;
#pragma unroll
    for (int off = 16; off > 0; off >>= 1) contrib += __shfl_xor(contrib, off, 64);
    if (tcc == 0) {
      Ms[hh] = Mg;
      Is[hh] = (contrib > 0.f) ? 1.f / contrib : 0.f;
    }
    __syncthreads();
    int t = tch * 256 + tid;
    float a = 0.f;
#pragma unroll
    for (int h = 0; h < NH; ++h) {
      float s = S[((size_t)(b * NH + h)) * NT + t];
      a += (s == -INFINITY) ? 0.f : __expf(s - Ms[h]) * Is[h];
    }
    ow[(size_t)b * NT + t] = a * 0.125f;
  }
}

// p2[b, hd] = xa[b,h,:].kv_w[NC+hd, :] + kv_b[NC+hd]  (wave per (b,hd))
__global__ __launch_bounds__(256) void k_pv(const float* __restrict__ xa,
                                            const float* __restrict__ kv_w,
                                            const float* __restrict__ kv_b,
                                            float* __restrict__ p2) {
  int gw = (blockIdx.x * 256 + threadIdx.x) >> 6;
  int lane = threadIdx.x & 63;
  if (gw >= NB * NC) return;
  int b = gw >> 10;
  int hd = gw & (NC - 1);
  int h = hd >> 7;
  const float4* a4 = (const float4*)(xa + ((size_t)(b * NH + h)) * NC);
  const float4* w4 = (const float4*)(kv_w + ((size_t)(NC + hd)) * NC);
  float acc = 0.f;
#pragma unroll
  for (int j = 0; j < 4; ++j) {
    float4 a = a4[lane + 64 * j];
    float4 w = w4[lane + 64 * j];
    acc += a.x * w.x + a.y * w.y + a.z * w.z + a.w * w.w;
  }
  acc = wredsum(acc);
  if (lane == 0) p2[(size_t)b * NC + hd] = acc + kv_b[NC + hd];
}

// out[b,i] = p2[b,:].proj_w[i,:] + proj_b[i]  (wave per (b,i))
__global__ __launch_bounds__(256) void k_proj(const float* __restrict__ p2,
                                              const float* __restrict__ proj_w,
                                              const float* __restrict__ proj_b,
                                              float* __restrict__ out) {
  int gw = (blockIdx.x * 256 + threadIdx.x) >> 6;
  int lane = threadIdx.x & 63;
  if (gw >= NB * NC) return;
  int b = gw >> 10;
  int i = gw & (NC - 1);
  const float4* a4 = (const float4*)(p2 + (size_t)b * NC);
  const float4* w4 = (const float4*)(proj_w + (size_t)i * NC);
  float acc = 0.f;
#pragma unroll
  for (int j = 0; j < 4; ++j) {
    float4 a = a4[lane + 64 * j];
    float4 w = w4[lane + 64 * j];
    acc += a.x * w.x + a.y * w.y + a.z * w.z + a.w * w.w;
  }
  acc = wredsum(acc);
  if (lane == 0) out[(size_t)b * NC + i] = acc + proj_b[i];
}

extern "C" void kernel_launch(void* const* d_in, const int* in_sizes, int n_in,
                              void* d_out, int out_size, void* d_ws, size_t ws_size,
                              hipStream_t stream) {
  const float* x = (const float*)d_in[0];
  const int* mask = (const int*)d_in[1];
  const float* qt = (const float*)d_in[2];
  const float* kv_w = (const float*)d_in[3];
  const float* kv_b = (const float*)d_in[4];
  const float* q_w = (const float*)d_in[5];
  const float* q_b = (const float*)d_in[6];
  const float* proj_w = (const float*)d_in[7];
  const float* proj_b = (const float*)d_in[8];
  float* out = (float*)d_out;

  float* ws = (float*)d_ws;
  float* q = ws;                    // 1024
  float* wqp = ws + 1024;           // 32768
  float* S = ws + 33792;            // 524288
  float* partAcc = ws + 558080;     // NB*TCH*NH*NC = 8388608 (32 MiB)
  float* partML = ws + 8946688;     // NB*TCH*NH*2 = 16384
  float* xa = ws + 8963072;         // 262144
  float* p2 = ws + 9225216;         // 32768

  k_wqp<<<32, 256, 0, stream>>>(qt, q_w, q_b, kv_w, q, wqp);
  k_fused<<<NB * TCH, 256, 0, stream>>>(x, mask, wqp, q, kv_b, S, partAcc, partML);
  k_xaw<<<512, 256, 0, stream>>>(partAcc, partML, S, xa, out + NB * NC);
  k_pv<<<(NB * NC) / 4, 256, 0, stream>>>(xa, kv_w, kv_b, p2);
  k_proj<<<(NB * NC) / 4, 256, 0, stream>>>(p2, proj_w, proj_b, out);
}

// Round 9
// 140.070 us; speedup vs baseline: 1.0790x; 1.0275x over previous
//
#include <hip/hip_runtime.h>
#include <math.h>

#define NB 32
#define NT 2048
#define NC 1024
#define NH 8
#define ND 128
#define TCH 32                       // t-chunks per batch; chunk = 64 rows
#define SCALE_F 0.08838834764831845f // 1/sqrt(128)

__device__ __forceinline__ float wredsum(float v) {
#pragma unroll
  for (int off = 32; off > 0; off >>= 1) v += __shfl_xor(v, off, 64);
  return v;
}

// raw barrier: lgkm-only wait (ds_writes visible), NO vmcnt drain.
// asm "memory" clobbers fence the compiler on both sides.
__device__ __forceinline__ void barx() {
  asm volatile("s_waitcnt lgkmcnt(0)" ::: "memory");
  __builtin_amdgcn_s_barrier();
  asm volatile("" ::: "memory");
}

// Fused q + split-K wq partial (unchanged, R7-validated).
__global__ __launch_bounds__(256) void k_wqp(const float* __restrict__ qt,
                                             const float* __restrict__ q_w,
                                             const float* __restrict__ q_b,
                                             const float* __restrict__ kv_w,
                                             float* __restrict__ qout,
                                             float* __restrict__ wqp) {
  __shared__ float qs[32];
  int h = blockIdx.x >> 2, dq = blockIdx.x & 3;
  int tid = threadIdx.x;
  int dbase = h * ND + dq * 32;
  {
    int row = tid >> 3;  // 32 rows x 8 threads
    int cg = tid & 7;
    const float4* qw4 = (const float4*)(q_w + (size_t)(dbase + row) * NC);
    const float4* qt4 = (const float4*)qt;
    float p = 0.f;
#pragma unroll 8
    for (int j = 0; j < 32; ++j) {
      float4 wv = qw4[cg * 32 + j];
      float4 av = qt4[cg * 32 + j];
      p += av.x * wv.x + av.y * wv.y + av.z * wv.z + av.w * wv.w;
    }
    p += __shfl_xor(p, 1, 64);
    p += __shfl_xor(p, 2, 64);
    p += __shfl_xor(p, 4, 64);
    if (cg == 0) qs[row] = p + q_b[dbase + row];
  }
  __syncthreads();
  if (tid < 32) qout[dbase + tid] = qs[tid];
  const float4* kw4 = (const float4*)kv_w;
  float4 acc = make_float4(0.f, 0.f, 0.f, 0.f);
#pragma unroll 8
  for (int dd = 0; dd < 32; ++dd) {
    float qv = qs[dd];
    float4 kv = kw4[(size_t)(dbase + dd) * 256 + tid];
    acc.x = fmaf(qv, kv.x, acc.x); acc.y = fmaf(qv, kv.y, acc.y);
    acc.z = fmaf(qv, kv.z, acc.z); acc.w = fmaf(qv, kv.w, acc.w);
  }
  ((float4*)wqp)[dq * 2048 + h * 256 + tid] = acc;
}

// Single pass over x. R6 geometry (TCH=32, 2-row steps, 16KB LDS dbuf).
// New: (a) ballot-mask -> loop has NO vmem except prefetch (kills the
// per-step vmcnt(0) drain at mask-use); (b) two-deep PA/PB prefetch with
// raw lgkm-only barrier -> ds_write waits counted vmcnt(2), barrier never
// drains the in-flight prefetch.
__global__ __launch_bounds__(256, 2) void k_fused(
    const float* __restrict__ x, const int* __restrict__ mask,
    const float* __restrict__ wqp, const float* __restrict__ q,
    const float* __restrict__ kv_b,
    float* __restrict__ S, float* __restrict__ partAcc,
    float* __restrict__ partML) {
  __shared__ float4 xs4[2 * 512];  // 2 slots x 2 rows x 256 float4 = 16 KB
  int bi = blockIdx.x;  // b*TCH + tc
  int b = bi >> 5;
  int tc = bi & (TCH - 1);
  int tid = threadIdx.x;
  int w = tid >> 6, lane = tid & 63;
  int h0 = w * 2;
  int tbase = tc * 64;

  // wq fragments (sum of 4 split-K partials; L2-hot)
  const float4* wqp4 = (const float4*)wqp;
  float4 wqv[2][4];
#pragma unroll
  for (int hh = 0; hh < 2; ++hh)
#pragma unroll
    for (int j = 0; j < 4; ++j) {
      int idx = (h0 + hh) * 256 + lane + 64 * j;
      float4 s0 = wqp4[idx], s1 = wqp4[2048 + idx];
      float4 s2 = wqp4[4096 + idx], s3 = wqp4[6144 + idx];
      wqv[hh][j] = make_float4((s0.x + s1.x) + (s2.x + s3.x),
                               (s0.y + s1.y) + (s2.y + s3.y),
                               (s0.z + s1.z) + (s2.z + s3.z),
                               (s0.w + s1.w) + (s2.w + s3.w));
    }
  // qkb[h] = q[h,:].kv_b[h,:] in-wave
  float qkbv[2];
#pragma unroll
  for (int hh = 0; hh < 2; ++hh) {
    float p = 0.f;
    if (lane < 32) {
      float4 qv = ((const float4*)(q + (h0 + hh) * ND))[lane];
      float4 bv = ((const float4*)(kv_b + (h0 + hh) * ND))[lane];
      p = qv.x * bv.x + qv.y * bv.y + qv.z * bv.z + qv.w * bv.w;
    }
    qkbv[hh] = wredsum(p);
  }
  // ballot-mask: whole chunk's mask as a wave-uniform 64-bit scalar
  unsigned long long bm = __ballot(mask[b * NT + tbase + lane] != 0);

  float m[2] = {-INFINITY, -INFINITY};
  float l[2] = {0.f, 0.f};
  float4 acc[2][4];
#pragma unroll
  for (int hh = 0; hh < 2; ++hh)
#pragma unroll
    for (int j = 0; j < 4; ++j) acc[hh][j] = make_float4(0.f, 0.f, 0.f, 0.f);
  float sreg[2][2] = {{0.f, 0.f}, {0.f, 0.f}};

  const float4* x4 = (const float4*)(x + (size_t)(b * NT + tbase) * NC);

  // prologue: stage rows 0,1 (step 0) into slot 0
  {
    float4 s0 = x4[tid], s1 = x4[256 + tid];
    xs4[tid] = s0;
    xs4[256 + tid] = s1;
  }
  barx();
  // two-deep prefetch: PA = step-1 rows, PB = step-2 rows (named regs)
  float4 pa0 = x4[2 * 256 + tid], pa1 = x4[3 * 256 + tid];
  float4 pb0 = x4[4 * 256 + tid], pb1 = x4[5 * 256 + tid];

#define COMPUTE_STEP(STEP, SLOT)                                               \
  {                                                                            \
    int t0 = tbase + (STEP) * 2;                                               \
    int mk0 = (int)((bm >> (unsigned)(2 * (STEP))) & 1ull);                    \
    int mk1 = (int)((bm >> (unsigned)(2 * (STEP) + 1)) & 1ull);                \
    float bias0 = 2.0f * __expf((float)t0 * (-3.0f / 2048.0f));                \
    float bias1 = 2.0f * __expf((float)(t0 + 1) * (-3.0f / 2048.0f));          \
    float4 xv[2][4];                                                           \
    _Pragma("unroll") for (int r = 0; r < 2; ++r)                              \
        _Pragma("unroll") for (int j = 0; j < 4; ++j)                          \
            xv[r][j] = xs4[(SLOT) * 512 + r * 256 + lane + 64 * j];            \
    _Pragma("unroll") for (int hh = 0; hh < 2; ++hh) {                         \
      float d0 = 0.f, d1 = 0.f;                                                \
      _Pragma("unroll") for (int j = 0; j < 4; ++j) {                          \
        float4 wv = wqv[hh][j];                                                \
        d0 = fmaf(xv[0][j].x, wv.x, d0); d0 = fmaf(xv[0][j].y, wv.y, d0);      \
        d0 = fmaf(xv[0][j].z, wv.z, d0); d0 = fmaf(xv[0][j].w, wv.w, d0);      \
        d1 = fmaf(xv[1][j].x, wv.x, d1); d1 = fmaf(xv[1][j].y, wv.y, d1);      \
        d1 = fmaf(xv[1][j].z, wv.z, d1); d1 = fmaf(xv[1][j].w, wv.w, d1);      \
      }                                                                        \
      d0 = wredsum(d0);                                                        \
      d1 = wredsum(d1);                                                        \
      float v0 = mk0 ? (d0 + qkbv[hh]) * SCALE_F + bias0 : -INFINITY;          \
      float v1 = mk1 ? (d1 + qkbv[hh]) * SCALE_F + bias1 : -INFINITY;          \
      sreg[hh][0] = (lane == (STEP)) ? v0 : sreg[hh][0];                       \
      sreg[hh][1] = (lane == (STEP)) ? v1 : sreg[hh][1];                       \
      float pmax = fmaxf(v0, v1);                                              \
      if (pmax > m[hh] + 8.0f) { /* defer-max; wave-uniform */                 \
        float r = __expf(m[hh] - pmax);                                        \
        l[hh] *= r;                                                            \
        _Pragma("unroll") for (int j = 0; j < 4; ++j) {                        \
          acc[hh][j].x *= r; acc[hh][j].y *= r;                                \
          acc[hh][j].z *= r; acc[hh][j].w *= r;                                \
        }                                                                      \
        m[hh] = pmax;                                                          \
      }                                                                        \
      float p0 = mk0 ? __expf(v0 - m[hh]) : 0.f;                               \
      float p1 = mk1 ? __expf(v1 - m[hh]) : 0.f;                               \
      l[hh] += p0 + p1;                                                        \
      _Pragma("unroll") for (int j = 0; j < 4; ++j) {                          \
        acc[hh][j].x = fmaf(p0, xv[0][j].x, fmaf(p1, xv[1][j].x, acc[hh][j].x)); \
        acc[hh][j].y = fmaf(p0, xv[0][j].y, fmaf(p1, xv[1][j].y, acc[hh][j].y)); \
        acc[hh][j].z = fmaf(p0, xv[0][j].z, fmaf(p1, xv[1][j].z, acc[hh][j].z)); \
        acc[hh][j].w = fmaf(p0, xv[0][j].w, fmaf(p1, xv[1][j].w, acc[hh][j].w)); \
      }                                                                        \
    }                                                                          \
  }

  for (int k = 0; k < 16; ++k) {
    // ---- substep A: step 2k, reads slot 0 ----
    COMPUTE_STEP(2 * k, 0)
    // write PA (= step 2k+1 rows, loaded a full step ago -> counted vmcnt)
    xs4[512 + tid] = pa0;
    xs4[512 + 256 + tid] = pa1;
    if (k < 15) {  // issue new PA = step 2k+3 rows
      pa0 = x4[(4 * k + 6) * 256 + tid];
      pa1 = x4[(4 * k + 7) * 256 + tid];
    }
    barx();
    // ---- substep B: step 2k+1, reads slot 1 ----
    COMPUTE_STEP(2 * k + 1, 1)
    if (k < 15) {  // write PB (= step 2k+2 rows)
      xs4[tid] = pb0;
      xs4[256 + tid] = pb1;
      if (k < 14) {  // issue new PB = step 2k+4 rows
        pb0 = x4[(4 * k + 8) * 256 + tid];
        pb1 = x4[(4 * k + 9) * 256 + tid];
      }
      barx();
    }
  }
#undef COMPUTE_STEP

  // raw-score store: ONLY lanes 0..31 own rows (R4 lesson)
  if (lane < 32) {
#pragma unroll
    for (int hh = 0; hh < 2; ++hh) {
      float2 sv = make_float2(sreg[hh][0], sreg[hh][1]);
      float2* sp = (float2*)(S + ((size_t)(b * NH + h0 + hh)) * NT + tbase);
      sp[lane] = sv;
    }
  }
  float4* pA = (float4*)(partAcc + (size_t)bi * (NH * NC));
#pragma unroll
  for (int hh = 0; hh < 2; ++hh)
#pragma unroll
    for (int j = 0; j < 4; ++j)
      pA[(h0 + hh) * 256 + lane + 64 * j] = acc[hh][j];
  if (lane == 0) {
#pragma unroll
    for (int hh = 0; hh < 2; ++hh) {
      partML[(bi * NH + h0 + hh) * 2] = m[hh];
      partML[(bi * NH + h0 + hh) * 2 + 1] = l[hh];
    }
  }
}

// Merged xa-reduce + attn_weights (unchanged from R8).
__global__ __launch_bounds__(256) void k_xaw(const float* __restrict__ partAcc,
                                             const float* __restrict__ partML,
                                             const float* __restrict__ S,
                                             float* __restrict__ xa,
                                             float* __restrict__ ow) {
  __shared__ float Ms[NH], Is[NH];
  int blk = blockIdx.x;
  int tid = threadIdx.x;
  if (blk < NB * NH) {  // ---- xa role ----
    int b = blk >> 3, h = blk & 7;
    float mv = -INFINITY, lv = 0.f;
    if (tid < 32) {
      mv = partML[((b * TCH + tid) * NH + h) * 2];
      lv = partML[((b * TCH + tid) * NH + h) * 2 + 1];
    }
    float Mg = mv;
#pragma unroll
    for (int off = 16; off > 0; off >>= 1) Mg = fmaxf(Mg, __shfl_xor(Mg, off, 64));
    float contrib = (tid < 32 && mv != -INFINITY) ? __expf(mv - Mg) * lv : 0.f;
#pragma unroll
    for (int off = 16; off > 0; off >>= 1) contrib += __shfl_xor(contrib, off, 64);
    if (tid == 0) {
      Ms[0] = Mg;
      Is[0] = (contrib > 0.f) ? 1.f / contrib : 0.f;
    }
    __syncthreads();
    float Mgb = Ms[0], inv = Is[0];
    float4 sacc = make_float4(0.f, 0.f, 0.f, 0.f);
    for (int tc = 0; tc < TCH; ++tc) {
      int pi = (b * TCH + tc) * NH + h;
      float mw = partML[pi * 2];
      if (mw == -INFINITY) continue;
      float scl = __expf(mw - Mgb);
      float4 v = ((const float4*)partAcc)[(size_t)pi * 256 + tid];
      sacc.x = fmaf(scl, v.x, sacc.x); sacc.y = fmaf(scl, v.y, sacc.y);
      sacc.z = fmaf(scl, v.z, sacc.z); sacc.w = fmaf(scl, v.w, sacc.w);
    }
    sacc.x *= inv; sacc.y *= inv; sacc.z *= inv; sacc.w *= inv;
    ((float4*)xa)[(size_t)blk * 256 + tid] = sacc;
  } else {  // ---- attn_weights role ----
    int blkb = blk - NB * NH;
    int b = blkb >> 3, tch = blkb & 7;
    int hh = tid >> 5, tcc = tid & 31;  // 8 heads x 32 chunks
    float mv = partML[((b * TCH + tcc) * NH + hh) * 2];
    float lv = partML[((b * TCH + tcc) * NH + hh) * 2 + 1];
    float Mg = mv;
#pragma unroll
    for (int off = 16; off > 0; off >>= 1) Mg = fmaxf(Mg, __shfl_xor(Mg, off, 64));
    float contrib = (mv != -INFINITY) ? __expf(mv - Mg) * lv : 0.f;
#pragma unroll
    for (int off = 16; off > 0; off >>= 1) contrib += __shfl_xor(contrib, off, 64);
    if (tcc == 0) {
      Ms[hh] = Mg;
      Is[hh] = (contrib > 0.f) ? 1.f / contrib : 0.f;
    }
    __syncthreads();
    int t = tch * 256 + tid;
    float a = 0.f;
#pragma unroll
    for (int h = 0; h < NH; ++h) {
      float s = S[((size_t)(b * NH + h)) * NT + t];
      a += (s == -INFINITY) ? 0.f : __expf(s - Ms[h]) * Is[h];
    }
    ow[(size_t)b * NT + t] = a * 0.125f;
  }
}

// p2[b, hd] = xa[b,h,:].kv_w[NC+hd, :] + kv_b[NC+hd]  (wave per (b,hd))
__global__ __launch_bounds__(256) void k_pv(const float* __restrict__ xa,
                                            const float* __restrict__ kv_w,
                                            const float* __restrict__ kv_b,
                                            float* __restrict__ p2) {
  int gw = (blockIdx.x * 256 + threadIdx.x) >> 6;
  int lane = threadIdx.x & 63;
  if (gw >= NB * NC) return;
  int b = gw >> 10;
  int hd = gw & (NC - 1);
  int h = hd >> 7;
  const float4* a4 = (const float4*)(xa + ((size_t)(b * NH + h)) * NC);
  const float4* w4 = (const float4*)(kv_w + ((size_t)(NC + hd)) * NC);
  float acc = 0.f;
#pragma unroll
  for (int j = 0; j < 4; ++j) {
    float4 a = a4[lane + 64 * j];
    float4 w = w4[lane + 64 * j];
    acc += a.x * w.x + a.y * w.y + a.z * w.z + a.w * w.w;
  }
  acc = wredsum(acc);
  if (lane == 0) p2[(size_t)b * NC + hd] = acc + kv_b[NC + hd];
}

// out[b,i] = p2[b,:].proj_w[i,:] + proj_b[i]  (wave per (b,i))
__global__ __launch_bounds__(256) void k_proj(const float* __restrict__ p2,
                                              const float* __restrict__ proj_w,
                                              const float* __restrict__ proj_b,
                                              float* __restrict__ out) {
  int gw = (blockIdx.x * 256 + threadIdx.x) >> 6;
  int lane = threadIdx.x & 63;
  if (gw >= NB * NC) return;
  int b = gw >> 10;
  int i = gw & (NC - 1);
  const float4* a4 = (const float4*)(p2 + (size_t)b * NC);
  const float4* w4 = (const float4*)(proj_w + (size_t)i * NC);
  float acc = 0.f;
#pragma unroll
  for (int j = 0; j < 4; ++j) {
    float4 a = a4[lane + 64 * j];
    float4 w = w4[lane + 64 * j];
    acc += a.x * w.x + a.y * w.y + a.z * w.z + a.w * w.w;
  }
  acc = wredsum(acc);
  if (lane == 0) out[(size_t)b * NC + i] = acc + proj_b[i];
}

extern "C" void kernel_launch(void* const* d_in, const int* in_sizes, int n_in,
                              void* d_out, int out_size, void* d_ws, size_t ws_size,
                              hipStream_t stream) {
  const float* x = (const float*)d_in[0];
  const int* mask = (const int*)d_in[1];
  const float* qt = (const float*)d_in[2];
  const float* kv_w = (const float*)d_in[3];
  const float* kv_b = (const float*)d_in[4];
  const float* q_w = (const float*)d_in[5];
  const float* q_b = (const float*)d_in[6];
  const float* proj_w = (const float*)d_in[7];
  const float* proj_b = (const float*)d_in[8];
  float* out = (float*)d_out;

  float* ws = (float*)d_ws;
  float* q = ws;                    // 1024
  float* wqp = ws + 1024;           // 32768
  float* S = ws + 33792;            // 524288
  float* partAcc = ws + 558080;     // NB*TCH*NH*NC = 8388608 (32 MiB)
  float* partML = ws + 8946688;     // NB*TCH*NH*2 = 16384
  float* xa = ws + 8963072;         // 262144
  float* p2 = ws + 9225216;         // 32768

  k_wqp<<<32, 256, 0, stream>>>(qt, q_w, q_b, kv_w, q, wqp);
  k_fused<<<NB * TCH, 256, 0, stream>>>(x, mask, wqp, q, kv_b, S, partAcc, partML);
  k_xaw<<<512, 256, 0, stream>>>(partAcc, partML, S, xa, out + NB * NC);
  k_pv<<<(NB * NC) / 4, 256, 0, stream>>>(xa, kv_w, kv_b, p2);
  k_proj<<<(NB * NC) / 4, 256, 0, stream>>>(p2, proj_w, proj_b, out);
}